// Round 7
// baseline (6386.988 us; speedup 1.0000x reference)
//
#include <hip/hip_runtime.h>
#include <hip/hip_fp16.h>
#include <math.h>

#define NN 1000
#define INF_ 32
#define H 128
#define M 128
#define DEG 16
#define PP 2
#define OUTF 10
#define MAXM (10 * NN)        // scan length; head <= MAXM
#define QCAP (MAXM + DEG)     // only entries < MAXM are ever read
#define NT 512
#define PB 128                // candidate cap per window
#define RC 8                  // rows per matvec chunk

// ws layout: feats[NN*H] f32 | final[NN*H] f32 | qm[QCAP*M] f32 | nmbuf[PB*M] f32
//            | wnsH[32*128] uint4 | wnmH[32*128] uint4 | qn[QCAP] u16

__global__ __launch_bounds__(128)
void init_kernel(const float* __restrict__ xa, const float* __restrict__ fm,
                 const float* __restrict__ enc_w, const float* __restrict__ enc_b,
                 const int* __restrict__ nstart_p,
                 float* __restrict__ feats, float* __restrict__ finalv,
                 float* __restrict__ qm) {
    int b = blockIdx.x, t = threadIdx.x;
    float acc = enc_b[t];
    const float* xr = xa + b * INF_;
#pragma unroll
    for (int k = 0; k < INF_; ++k) acc += xr[k] * enc_w[k * H + t];
    feats[b * H + t] = acc;
    finalv[b * H + t] = 0.0f;
    if (b < nstart_p[0]) qm[(size_t)b * M + t] = fm[b * M + t];
}

// Pack weights to fp16, K-major x8: wH[j8*128+col] = halves of w[8j8..8j8+8)[col]
__global__ __launch_bounds__(256)
void pack_kernel(const float* __restrict__ ns_w, const float* __restrict__ nm_w,
                 uint4* __restrict__ wnsH, uint4* __restrict__ wnmH) {
    const int idx = blockIdx.x * 256 + threadIdx.x;   // 32*128 = 4096
    if (idx >= 32 * 128) return;
    const int j8 = idx >> 7, col = idx & 127;
    unsigned int a[4], b[4];
#pragma unroll
    for (int p = 0; p < 4; ++p) {
        unsigned int l0 = __half_as_ushort(__float2half_rn(ns_w[(8*j8 + 2*p    ) * H + col]));
        unsigned int h0 = __half_as_ushort(__float2half_rn(ns_w[(8*j8 + 2*p + 1) * H + col]));
        a[p] = l0 | (h0 << 16);
        unsigned int l1 = __half_as_ushort(__float2half_rn(nm_w[(8*j8 + 2*p    ) * M + col]));
        unsigned int h1 = __half_as_ushort(__float2half_rn(nm_w[(8*j8 + 2*p + 1) * M + col]));
        b[p] = l1 | (h1 << 16);
    }
    wnsH[idx] = make_uint4(a[0], a[1], a[2], a[3]);
    wnmH[idx] = make_uint4(b[0], b[1], b[2], b[3]);
}

__device__ __forceinline__ void unpack8(const uint4 q, float w[8]) {
    const __half2* h = reinterpret_cast<const __half2*>(&q);
    float2 f;
    f = __half22float2(h[0]); w[0] = f.x; w[1] = f.y;
    f = __half22float2(h[1]); w[2] = f.x; w[3] = f.y;
    f = __half22float2(h[2]); w[4] = f.x; w[5] = f.y;
    f = __half22float2(h[3]); w[6] = f.x; w[7] = f.y;
}

// Rank-decomposed sequential ACT loop with LDS-resident fp16 weights.
__global__ __launch_bounds__(NT, 1)
void seq_kernel(const int* __restrict__ neighbors,
                const float* __restrict__ ns_b, const float* __restrict__ nm_b,
                const float* __restrict__ act_w, const float* __restrict__ act_b,
                const float* __restrict__ dec_w, const float* __restrict__ dec_b,
                const int* __restrict__ nstart_p,
                const uint4* __restrict__ wnsH, const uint4* __restrict__ wnmH,
                float* __restrict__ feats, float* __restrict__ finalv,
                float* __restrict__ qm, float* __restrict__ nmbuf,
                unsigned short* __restrict__ qn, float* __restrict__ out) {
    __shared__ uint4 s_wn[32 * 128];                 // 64 KB fp16 ns_w
    __shared__ uint4 s_wm[32 * 128];                 // 64 KB fp16 nm_w
    __shared__ float s_tact[NN];                     // 4000 B
    __shared__ __align__(16) float s_X[RC][H + M];   // 8 KB (mark overlaid)
    __shared__ __align__(16) float s_NS[RC][H];      // 4 KB
    __shared__ __align__(16) float s_NM[RC][M];      // 4 KB
    __shared__ float s_actw[H + M];
    __shared__ float s_nsb[H];
    __shared__ float s_nmb[M];
    __shared__ float s_rz[RC];
    __shared__ float s_rna[RC];
    __shared__ unsigned short s_rnode[PB];
    __shared__ unsigned short s_rentry[PB];
    __shared__ short s_eslot[NT];
    __shared__ unsigned char s_flag[NT];
    __shared__ short s_order[PB];
    __shared__ int   s_wa[8], s_wb[8], s_wc[8];
    __shared__ int   s_cut;
    __shared__ float s_g[H];
    __shared__ float s_lg[PP * OUTF];

    int* s_mark = (int*)&s_X[0][0];                  // overlay: dead when X live

    const int t = threadIdx.x;
    const int lane = t & 63, wid = t >> 6;
    const int col = t & 127, g = t >> 7;             // matvec mapping (2 rows/thread)
    const int nstart = nstart_p[0];

    for (int i = t; i < 32 * 128; i += NT) { s_wn[i] = wnsH[i]; s_wm[i] = wnmH[i]; }
    for (int i = t; i < NN; i += NT) s_tact[i] = 0.0f;
    for (int i = t; i < nstart; i += NT) qn[i] = (unsigned short)i;
    if (t < H + M) s_actw[t] = act_w[t];
    if (t < H) { s_nsb[t] = ns_b[t]; s_nmb[t] = nm_b[t]; }
    const float actb = act_b[0];
    __syncthreads();
    const float nsb_c = s_nsb[col];
    const float nmb_c = s_nmb[col];

    int head = 0, tail = nstart;
    for (;;) {
        const int lim = min(tail, MAXM);
        if (head >= lim) break;
        const int W = min(NT, lim - head);

        // ---- classify candidates; cut at (PB+1)-th candidate ----
        int node = 0; bool cand0 = false;
        if (t < W) {
            node = (int)qn[head + t];
            cand0 = (s_tact[node] <= 1.0f - 1e-7f);
        }
        const unsigned long long mc = __ballot(cand0);
        if (lane == 0) s_wa[wid] = __popcll(mc);
        if (t == 0) s_cut = 0x7fffffff;
        s_flag[t] = 0;
        __syncthreads();                              // B1
        int pre = 0;
#pragma unroll
        for (int w = 0; w < 8; ++w) pre += (w < wid) ? s_wa[w] : 0;
        const int crank = pre + __popcll(mc & ((1ull << lane) - 1ull));
        if (cand0 && crank == PB) s_cut = t;          // unique writer
        __syncthreads();                              // B2
        const int Wp = min(W, s_cut);
        bool remaining = cand0 && (t < Wp);

        // ---------------- rank rounds ----------------
        int base = 0;
        for (;;) {
            for (int i = t; i < NN; i += NT) s_mark[i] = 0x7fffffff;  // re-init (X dead)
            __syncthreads();                          // R0
            const bool rem2 = remaining && (s_tact[node] <= 1.0f - 1e-7f);
            if (rem2) atomicMin(&s_mark[node], t);
            __syncthreads();                          // R1
            const bool win = rem2 && (s_mark[node] == t);
            const unsigned long long mw = __ballot(win);
            if (lane == 0) s_wb[wid] = __popcll(mw);
            __syncthreads();                          // R2
            int Pr = 0, preb = 0;
#pragma unroll
            for (int w = 0; w < 8; ++w) { Pr += s_wb[w]; preb += (w < wid) ? s_wb[w] : 0; }
            if (Pr == 0) break;
            const int wrank = preb + __popcll(mw & ((1ull << lane) - 1ull));
            if (win) {
                s_rnode[wrank] = (unsigned short)node;
                s_rentry[wrank] = (unsigned short)t;
                s_eslot[t] = (short)(base + wrank);
                s_flag[t] = 1;
            }
            remaining = rem2 && !win;
            __syncthreads();                          // R3 (rnode/rentry ready; mark dead)

            // ---- chunks of RC rows ----
            for (int c0 = 0; c0 < Pr; c0 += RC) {
                const int Pc = min(RC, Pr - c0);
                // stage X rows
                for (int idx = t; idx < Pc * 64; idx += NT) {
                    const int r = idx >> 6, c4 = idx & 63;
                    const int nr = (int)s_rnode[c0 + r];
                    const int hp = head + (int)s_rentry[c0 + r];
                    float4 v;
                    if (c4 < 32) v = ((const float4*)(feats + (size_t)nr * H))[c4];
                    else         v = ((const float4*)(qm + (size_t)hp * M))[c4 - 32];
                    ((float4*)&s_X[r][0])[c4] = v;
                }
                __syncthreads();                      // A

                // gate partials (exact R4/R6 arithmetic)
                {
                    const int r = t >> 5, sg = t & 31;
                    if (r < Pc) {
                        const float* xr = &s_X[r][0];
                        float p = 0.0f;
#pragma unroll
                        for (int j = 0; j < 8; ++j)
                            p += xr[sg * 8 + j] * s_actw[sg * 8 + j];
#pragma unroll
                        for (int off = 16; off > 0; off >>= 1) p += __shfl_down(p, off, 32);
                        if (sg == 0) s_rz[r] = p;
                    }
                }
                // phase 1: ns full-K + nm msg-half; rows g, g+4; weights from LDS
                float nsv0, nsv1, am0 = 0.0f, am1 = 0.0f;
                {
                    const float4* X0 = (const float4*)&s_X[g][0];
                    const float4* X1 = (const float4*)&s_X[g + 4][0];
                    float an0 = 0.0f, an1 = 0.0f;
                    float w[8], m[8];
#pragma unroll 8
                    for (int j8 = 0; j8 < 16; ++j8) {         // k in [0,128): ns only
                        unpack8(s_wn[j8 * 128 + col], w);
                        const float4 a0 = X0[2*j8], b0 = X0[2*j8+1];
                        const float4 a1 = X1[2*j8], b1 = X1[2*j8+1];
                        an0 += a0.x*w[0] + a0.y*w[1] + a0.z*w[2] + a0.w*w[3]
                             + b0.x*w[4] + b0.y*w[5] + b0.z*w[6] + b0.w*w[7];
                        an1 += a1.x*w[0] + a1.y*w[1] + a1.z*w[2] + a1.w*w[3]
                             + b1.x*w[4] + b1.y*w[5] + b1.z*w[6] + b1.w*w[7];
                    }
#pragma unroll 8
                    for (int j8 = 16; j8 < 32; ++j8) {        // k in [128,256): ns + nm msg
                        unpack8(s_wn[j8 * 128 + col], w);
                        unpack8(s_wm[j8 * 128 + col], m);
                        const float4 a0 = X0[2*j8], b0 = X0[2*j8+1];
                        const float4 a1 = X1[2*j8], b1 = X1[2*j8+1];
                        an0 += a0.x*w[0] + a0.y*w[1] + a0.z*w[2] + a0.w*w[3]
                             + b0.x*w[4] + b0.y*w[5] + b0.z*w[6] + b0.w*w[7];
                        an1 += a1.x*w[0] + a1.y*w[1] + a1.z*w[2] + a1.w*w[3]
                             + b1.x*w[4] + b1.y*w[5] + b1.z*w[6] + b1.w*w[7];
                        am0 += a0.x*m[0] + a0.y*m[1] + a0.z*m[2] + a0.w*m[3]
                             + b0.x*m[4] + b0.y*m[5] + b0.z*m[6] + b0.w*m[7];
                        am1 += a1.x*m[0] + a1.y*m[1] + a1.z*m[2] + a1.w*m[3]
                             + b1.x*m[4] + b1.y*m[5] + b1.z*m[6] + b1.w*m[7];
                    }
                    nsv0 = fmaxf(an0 + nsb_c, 0.0f);
                    nsv1 = fmaxf(an1 + nsb_c, 0.0f);
                    if (g     < Pc) s_NS[g    ][col] = nsv0;
                    if (g + 4 < Pc) s_NS[g + 4][col] = nsv1;
                }
                __syncthreads();                      // B: NS + rz ready

                // gate finalize + tact (distinct nodes per round)
                if (t < Pc) {
                    const float z = s_rz[t] + actb;
                    const float cnd = 1.0f / (1.0f + expf(-z));
                    const int nr = (int)s_rnode[c0 + t];
                    const float ta = s_tact[nr];
                    const float na = (ta + cnd > 1.0f) ? (1.0f - ta) : cnd;
                    s_rna[t] = na;
                    s_tact[nr] = ta + na;
                }
                // phase 2: nm ns-half
                {
                    const float4* N0 = (const float4*)&s_NS[g][0];
                    const float4* N1 = (const float4*)&s_NS[g + 4][0];
                    float m[8];
#pragma unroll 8
                    for (int j8 = 0; j8 < 16; ++j8) {         // k in [0,128)
                        unpack8(s_wm[j8 * 128 + col], m);
                        const float4 a0 = N0[2*j8], b0 = N0[2*j8+1];
                        const float4 a1 = N1[2*j8], b1 = N1[2*j8+1];
                        am0 += a0.x*m[0] + a0.y*m[1] + a0.z*m[2] + a0.w*m[3]
                             + b0.x*m[4] + b0.y*m[5] + b0.z*m[6] + b0.w*m[7];
                        am1 += a1.x*m[0] + a1.y*m[1] + a1.z*m[2] + a1.w*m[3]
                             + b1.x*m[4] + b1.y*m[5] + b1.z*m[6] + b1.w*m[7];
                    }
                    if (g     < Pc) s_NM[g    ][col] = am0 + nmb_c;
                    if (g + 4 < Pc) s_NM[g + 4][col] = am1 + nmb_c;
                }
                __syncthreads();                      // C: rna + NM ready

                // updates: feats/final; NM -> global slot buffer
                if (g < Pc) {
                    const int nr = (int)s_rnode[c0 + g];
                    feats[(size_t)nr * H + col] = nsv0;
                    finalv[(size_t)nr * H + col] += nsv0 * s_rna[g];
                }
                if (g + 4 < Pc) {
                    const int nr = (int)s_rnode[c0 + g + 4];
                    feats[(size_t)nr * H + col] = nsv1;
                    finalv[(size_t)nr * H + col] += nsv1 * s_rna[g + 4];
                }
                for (int idx = t; idx < Pc * 32; idx += NT) {
                    const int r = idx >> 5, c4 = idx & 31;
                    ((float4*)nmbuf)[(size_t)(base + c0 + r) * 32 + c4] =
                        ((const float4*)&s_NM[r][0])[c4];
                }
                // no barrier: next chunk's X-stage doesn't touch NS/NM/rna regions,
                // and its own barriers order everything.
            }
            base += Pr;
        }

        // ---------------- enqueue (queue order via prefix over flags) ----------------
        const bool pf = (s_flag[t] != 0);
        const unsigned long long mf = __ballot(pf);
        if (lane == 0) s_wc[wid] = __popcll(mf);
        __syncthreads();                              // B3
        int T = 0, prec = 0;
#pragma unroll
        for (int w = 0; w < 8; ++w) { T += s_wc[w]; prec += (w < wid) ? s_wc[w] : 0; }
        if (pf) s_order[prec + __popcll(mf & ((1ull << lane) - 1ull))] = (short)t;
        __syncthreads();                              // B4
        for (int idx = t; idx < T * DEG; idx += NT) {
            const int j = idx >> 4;
            const int nd = (int)qn[head + (int)s_order[j]];
            const int q = tail + idx;
            if (q < QCAP)
                qn[q] = (unsigned short)neighbors[nd * DEG + (idx & 15)];
        }
        {
            float4* qm4 = (float4*)qm;
            const float4* nb4 = (const float4*)nmbuf;
            const int total = T * DEG * 32;
            for (int idx = t; idx < total; idx += NT) {
                const int c4 = idx & 31;
                const int row = idx >> 5;
                const int slot = (int)s_eslot[(int)s_order[row >> 4]];
                const int q = tail + row;
                if (q < QCAP)
                    qm4[(size_t)q * 32 + c4] = nb4[(size_t)slot * 32 + c4];
            }
        }
        tail += DEG * T;
        head += Wp;
        __syncthreads();                              // B5
    }

    // ---- readout ----
    if (t < H) {
        float g0 = 0, g1 = 0, g2 = 0, g3 = 0;
        for (int n = 0; n < NN; n += 4) {
            g0 += finalv[(n + 0) * H + t];
            g1 += finalv[(n + 1) * H + t];
            g2 += finalv[(n + 2) * H + t];
            g3 += finalv[(n + 3) * H + t];
        }
        s_g[t] = (g0 + g1) + (g2 + g3);
    }
    __syncthreads();
    if (t < PP * OUTF) {
        const int pp = t / OUTF, o = t % OUTF;
        float acc = dec_b[pp * OUTF + o];
        for (int h = 0; h < H; ++h) acc += s_g[h] * dec_w[(pp * H + h) * OUTF + o];
        s_lg[t] = acc;
    }
    __syncthreads();
    if (t < PP * OUTF) {
        const int pp = t / OUTF;
        float mx = -INFINITY;
        for (int o = 0; o < OUTF; ++o) mx = fmaxf(mx, s_lg[pp * OUTF + o]);
        float s = 0.0f;
        for (int o = 0; o < OUTF; ++o) s += expf(s_lg[pp * OUTF + o] - mx);
        out[t] = s_lg[t] - (mx + logf(s));
    }
}

extern "C" void kernel_launch(void* const* d_in, const int* in_sizes, int n_in,
                              void* d_out, int out_size, void* d_ws, size_t ws_size,
                              hipStream_t stream) {
    const float* xa        = (const float*)d_in[0];
    const float* fm        = (const float*)d_in[1];
    const int*   neighbors = (const int*)  d_in[2];
    const int*   nstart_p  = (const int*)  d_in[3];
    const float* enc_w     = (const float*)d_in[4];
    const float* enc_b     = (const float*)d_in[5];
    const float* ns_w      = (const float*)d_in[6];
    const float* ns_b      = (const float*)d_in[7];
    const float* nm_w      = (const float*)d_in[8];
    const float* nm_b      = (const float*)d_in[9];
    const float* act_w     = (const float*)d_in[10];
    const float* act_b     = (const float*)d_in[11];
    const float* dec_w     = (const float*)d_in[12];
    const float* dec_b     = (const float*)d_in[13];
    float* out = (float*)d_out;

    float* feats  = (float*)d_ws;                       // NN*H
    float* finalv = feats + NN * H;                     // NN*H
    float* qm     = finalv + NN * H;                    // QCAP*M
    float* nmbuf  = qm + (size_t)QCAP * M;              // PB*M
    uint4* wnsH   = (uint4*)(nmbuf + PB * M);           // 32*128 uint4
    uint4* wnmH   = wnsH + 32 * 128;
    unsigned short* qn = (unsigned short*)(wnmH + 32 * 128);  // QCAP u16

    init_kernel<<<NN, 128, 0, stream>>>(xa, fm, enc_w, enc_b, nstart_p,
                                        feats, finalv, qm);
    pack_kernel<<<16, 256, 0, stream>>>(ns_w, nm_w, wnsH, wnmH);
    seq_kernel<<<1, NT, 0, stream>>>(neighbors, ns_b, nm_b,
                                     act_w, act_b, dec_w, dec_b, nstart_p,
                                     wnsH, wnmH,
                                     feats, finalv, qm, nmbuf, qn, out);
}

// Round 8
// 1436.557 us; speedup vs baseline: 4.4460x; 4.4460x over previous
//
#include <hip/hip_runtime.h>
#include <math.h>

#define NN 1000
#define INF_ 32
#define H 128
#define M 128
#define DEG 16
#define PP 2
#define OUTF 10
#define MAXM (10 * NN)        // scan length; head <= MAXM
#define QCAP (MAXM + DEG)     // only entries < MAXM are ever read
#define NT 512
#define PB 128                // candidate cap per window (== nmbuf rows)
#define WROW 264              // padded halves per X/weight row (256+8)
#define NROW 136              // padded halves per NSh row (128+8)

typedef _Float16 half8 __attribute__((ext_vector_type(8)));
typedef float floatx4 __attribute__((ext_vector_type(4)));

// ws: feats[NN*H] f32 | final[NN*H] f32 | qm[QCAP*M] f32 | nmbuf[PB*M] f32
//     | wnsB[128*WROW] f16 | wnmB[128*WROW] f16 | qn[QCAP] u16

__global__ __launch_bounds__(128)
void init_kernel(const float* __restrict__ xa, const float* __restrict__ fm,
                 const float* __restrict__ enc_w, const float* __restrict__ enc_b,
                 const int* __restrict__ nstart_p,
                 float* __restrict__ feats, float* __restrict__ finalv,
                 float* __restrict__ qm) {
    int b = blockIdx.x, t = threadIdx.x;
    float acc = enc_b[t];
    const float* xr = xa + b * INF_;
#pragma unroll
    for (int k = 0; k < INF_; ++k) acc += xr[k] * enc_w[k * H + t];
    feats[b * H + t] = acc;
    finalv[b * H + t] = 0.0f;
    if (b < nstart_p[0]) qm[(size_t)b * M + t] = fm[b * M + t];
}

// Pack weights fp16 transposed [n][k] with +8 pad: wB[n*WROW+k] = w[k][n].
__global__ __launch_bounds__(256)
void pack_kernel(const float* __restrict__ ns_w, const float* __restrict__ nm_w,
                 _Float16* __restrict__ wnsB, _Float16* __restrict__ wnmB) {
    const int idx = blockIdx.x * 256 + threadIdx.x;   // 128*WROW
    if (idx >= 128 * WROW) return;
    const int n = idx / WROW, k = idx % WROW;
    wnsB[idx] = (k < 256) ? (_Float16)ns_w[k * H + n] : (_Float16)0.0f;
    wnmB[idx] = (k < 256) ? (_Float16)nm_w[k * M + n] : (_Float16)0.0f;
}

// Rank-decomposed sequential ACT loop; batched matvec on the MFMA pipe.
// Layouts (HW-verified m89/m91/m120): A[m=lane&15][k=quad*8+j],
// B[k=quad*8+j][n=lane&15], D col=lane&15, row=quad*4+reg.
__global__ __launch_bounds__(NT, 1)
void seq_kernel(const int* __restrict__ neighbors,
                const float* __restrict__ ns_b, const float* __restrict__ nm_b,
                const float* __restrict__ act_w, const float* __restrict__ act_b,
                const float* __restrict__ dec_w, const float* __restrict__ dec_b,
                const int* __restrict__ nstart_p,
                const _Float16* __restrict__ wnsB, const _Float16* __restrict__ wnmB,
                float* __restrict__ feats, float* __restrict__ finalv,
                float* __restrict__ qm, float* __restrict__ nmbuf,
                unsigned short* __restrict__ qn, float* __restrict__ out) {
    __shared__ __align__(16) _Float16 s_wn[128 * WROW];  // 67584 B
    __shared__ __align__(16) _Float16 s_wm[128 * WROW];  // 67584 B
    __shared__ __align__(16) _Float16 s_Xh[16 * WROW];   // 8448 B
    __shared__ __align__(16) _Float16 s_NSh[16 * NROW];  // 4352 B
    __shared__ float s_tact[NN];                         // 4000 B
    __shared__ int   s_mark[NN];                         // 4000 B
    __shared__ float s_actw[H + M];
    __shared__ float s_nsb[H];
    __shared__ float s_nmb[M];
    __shared__ float s_rz[16];
    __shared__ float s_rna[16];
    __shared__ unsigned short s_rnode[PB];
    __shared__ unsigned short s_rentry[PB];
    __shared__ short s_eslot[NT];
    __shared__ unsigned char s_flag[NT];
    __shared__ short s_order[PB];
    __shared__ int   s_wa[8], s_wb[8], s_wc[8];
    __shared__ int   s_cut;
    __shared__ float s_g[H];
    __shared__ float s_lg[PP * OUTF];

    const int t = threadIdx.x;
    const int lane = t & 63, wid = t >> 6;
    const int quad = lane >> 4, lm = lane & 15;
    const int colw = (wid << 4) + lm;                    // this thread's output col
    const int nstart = nstart_p[0];

    {   // one-time: weights into LDS (uint4 copies)
        const uint4* s0 = (const uint4*)wnsB; uint4* d0 = (uint4*)s_wn;
        const uint4* s1 = (const uint4*)wnmB; uint4* d1 = (uint4*)s_wm;
        for (int i = t; i < 128 * WROW / 8; i += NT) { d0[i] = s0[i]; d1[i] = s1[i]; }
    }
    for (int i = t; i < NN; i += NT) { s_tact[i] = 0.0f; s_mark[i] = 0x7fffffff; }
    for (int i = t; i < nstart; i += NT) qn[i] = (unsigned short)i;
    if (t < H + M) s_actw[t] = act_w[t];
    if (t < H) { s_nsb[t] = ns_b[t]; s_nmb[t] = nm_b[t]; }
    const float actb = act_b[0];
    __syncthreads();
    const float nsb_c = s_nsb[colw];
    const float nmb_c = s_nmb[colw];

    int head = 0, tail = nstart;
    for (;;) {
        const int lim = min(tail, MAXM);
        if (head >= lim) break;
        const int W = min(NT, lim - head);

        // ---- classify candidates; cut at (PB+1)-th candidate ----
        int node = 0; bool cand0 = false;
        if (t < W) {
            node = (int)qn[head + t];
            cand0 = (s_tact[node] <= 1.0f - 1e-7f);
        }
        const unsigned long long mc = __ballot(cand0);
        if (lane == 0) s_wa[wid] = __popcll(mc);
        if (t == 0) s_cut = 0x7fffffff;
        s_flag[t] = 0;
        __syncthreads();                              // B1
        int pre = 0;
#pragma unroll
        for (int w = 0; w < 8; ++w) pre += (w < wid) ? s_wa[w] : 0;
        const int crank = pre + __popcll(mc & ((1ull << lane) - 1ull));
        if (cand0 && crank == PB) s_cut = t;
        __syncthreads();                              // B2
        const int Wp = min(W, s_cut);
        bool remaining = cand0 && (t < Wp);

        // ---------------- rank rounds ----------------
        int base = 0;
        for (;;) {
            const bool rem2 = remaining && (s_tact[node] <= 1.0f - 1e-7f);
            if (rem2) atomicMin(&s_mark[node], t);
            __syncthreads();                          // R1
            const bool win = rem2 && (s_mark[node] == t);
            const unsigned long long mw = __ballot(win);
            if (lane == 0) s_wb[wid] = __popcll(mw);
            __syncthreads();                          // R2
            int Pr = 0, preb = 0;
#pragma unroll
            for (int w = 0; w < 8; ++w) { Pr += s_wb[w]; preb += (w < wid) ? s_wb[w] : 0; }
            if (Pr == 0) break;
            const int wrank = preb + __popcll(mw & ((1ull << lane) - 1ull));
            if (win) {
                s_rnode[wrank] = (unsigned short)node;
                s_rentry[wrank] = (unsigned short)t;
                s_eslot[t] = (short)(base + wrank);
                s_flag[t] = 1;
            }
            if (rem2) s_mark[node] = 0x7fffffff;      // reset only touched entries
            remaining = rem2 && !win;
            __syncthreads();                          // R3

            // ---- chunks of 16 rows ----
            for (int c0 = 0; c0 < Pr; c0 += 16) {
                const int Pc = min(16, Pr - c0);
                // stage Xh rows (f32 -> fp16), 8 halves per thread-iter
                for (int idx = t; idx < Pc * 32; idx += NT) {
                    const int r = idx >> 5, c8 = idx & 31;
                    const int nr = (int)s_rnode[c0 + r];
                    const int hp = head + (int)s_rentry[c0 + r];
                    const float4* src = (c8 < 16)
                        ? (const float4*)(feats + (size_t)nr * H) + (c8 << 1)
                        : (const float4*)(qm + (size_t)hp * M) + ((c8 - 16) << 1);
                    const float4 va = src[0], vb = src[1];
                    half8 h;
                    h[0]=(_Float16)va.x; h[1]=(_Float16)va.y; h[2]=(_Float16)va.z; h[3]=(_Float16)va.w;
                    h[4]=(_Float16)vb.x; h[5]=(_Float16)vb.y; h[6]=(_Float16)vb.z; h[7]=(_Float16)vb.w;
                    *(half8*)(s_Xh + r * WROW + (c8 << 3)) = h;
                }
                __syncthreads();                      // A: Xh ready

                // gate partials from fp16 x (f32 arithmetic)
                {
                    const int r = t >> 5, sg = t & 31;
                    if (r < Pc) {
                        const _Float16* xr = s_Xh + r * WROW;
                        float p = 0.0f;
#pragma unroll
                        for (int j = 0; j < 8; ++j)
                            p += (float)xr[sg * 8 + j] * s_actw[sg * 8 + j];
#pragma unroll
                        for (int off = 16; off > 0; off >>= 1) p += __shfl_down(p, off, 32);
                        if (sg == 0) s_rz[r] = p;
                    }
                }
                // phase 1 MFMA: ns (K=256) + nm msg-half (K=128..256)
                floatx4 accn = {0.0f, 0.0f, 0.0f, 0.0f};
                floatx4 accm = {0.0f, 0.0f, 0.0f, 0.0f};
                {
                    const _Float16* xrow = s_Xh + lm * WROW + (quad << 3);
                    const _Float16* bn = s_wn + colw * WROW + (quad << 3);
                    const _Float16* bm = s_wm + colw * WROW + (quad << 3);
                    half8 a[8];
#pragma unroll
                    for (int c = 0; c < 8; ++c) a[c] = *(const half8*)(xrow + (c << 5));
#pragma unroll
                    for (int c = 0; c < 8; ++c)
                        accn = __builtin_amdgcn_mfma_f32_16x16x32_f16(
                            a[c], *(const half8*)(bn + (c << 5)), accn, 0, 0, 0);
#pragma unroll
                    for (int c = 4; c < 8; ++c)
                        accm = __builtin_amdgcn_mfma_f32_16x16x32_f16(
                            a[c], *(const half8*)(bm + (c << 5)), accm, 0, 0, 0);
                }
                float nsv[4];
#pragma unroll
                for (int i = 0; i < 4; ++i) {
                    const int r = (quad << 2) + i;
                    nsv[i] = fmaxf(accn[i] + nsb_c, 0.0f);
                    if (r < Pc) {
                        s_NSh[r * NROW + colw] = (_Float16)nsv[i];
                        feats[(size_t)s_rnode[c0 + r] * H + colw] = nsv[i];
                    }
                }
                __syncthreads();                      // B: NSh + rz ready

                // gate finalize + tact (distinct nodes per round)
                if (t < Pc) {
                    const float z = s_rz[t] + actb;
                    const float cnd = 1.0f / (1.0f + expf(-z));
                    const int nr = (int)s_rnode[c0 + t];
                    const float ta = s_tact[nr];
                    const float na = (ta + cnd > 1.0f) ? (1.0f - ta) : cnd;
                    s_rna[t] = na;
                    s_tact[nr] = ta + na;
                }
                // phase 2 MFMA: nm ns-half (K=0..128)
                {
                    const _Float16* nrow = s_NSh + lm * NROW + (quad << 3);
                    const _Float16* bm = s_wm + colw * WROW + (quad << 3);
#pragma unroll
                    for (int c = 0; c < 4; ++c)
                        accm = __builtin_amdgcn_mfma_f32_16x16x32_f16(
                            *(const half8*)(nrow + (c << 5)),
                            *(const half8*)(bm + (c << 5)), accm, 0, 0, 0);
                }
                __syncthreads();                      // C: rna ready

                // epilogue: finalv + nmbuf
#pragma unroll
                for (int i = 0; i < 4; ++i) {
                    const int r = (quad << 2) + i;
                    if (r < Pc) {
                        finalv[(size_t)s_rnode[c0 + r] * H + colw] += nsv[i] * s_rna[r];
                        nmbuf[(size_t)(base + c0 + r) * M + colw] = accm[i] + nmb_c;
                    }
                }
            }
            base += Pr;
            __syncthreads();                          // R7: epilogue done before next round
        }

        // ---------------- enqueue (queue order via prefix over flags) ----------------
        const bool pf = (s_flag[t] != 0);
        const unsigned long long mf = __ballot(pf);
        if (lane == 0) s_wc[wid] = __popcll(mf);
        __syncthreads();                              // B3
        int T = 0, prec = 0;
#pragma unroll
        for (int w = 0; w < 8; ++w) { T += s_wc[w]; prec += (w < wid) ? s_wc[w] : 0; }
        if (pf) s_order[prec + __popcll(mf & ((1ull << lane) - 1ull))] = (short)t;
        __syncthreads();                              // B4
        for (int idx = t; idx < T * DEG; idx += NT) {
            const int j = idx >> 4;
            const int nd = (int)qn[head + (int)s_order[j]];
            const int q = tail + idx;
            if (q < QCAP)
                qn[q] = (unsigned short)neighbors[nd * DEG + (idx & 15)];
        }
        {
            float4* qm4 = (float4*)qm;
            const float4* nb4 = (const float4*)nmbuf;
            const int total = T * DEG * 32;
            for (int idx = t; idx < total; idx += NT) {
                const int c4 = idx & 31;
                const int row = idx >> 5;
                const int slot = (int)s_eslot[(int)s_order[row >> 4]];
                const int q = tail + row;
                if (q < QCAP)
                    qm4[(size_t)q * 32 + c4] = nb4[(size_t)slot * 32 + c4];
            }
        }
        tail += DEG * T;
        head += Wp;
        __syncthreads();                              // B5
    }

    // ---- readout ----
    if (t < H) {
        float g0 = 0, g1 = 0, g2 = 0, g3 = 0;
        for (int n = 0; n < NN; n += 4) {
            g0 += finalv[(n + 0) * H + t];
            g1 += finalv[(n + 1) * H + t];
            g2 += finalv[(n + 2) * H + t];
            g3 += finalv[(n + 3) * H + t];
        }
        s_g[t] = (g0 + g1) + (g2 + g3);
    }
    __syncthreads();
    if (t < PP * OUTF) {
        const int pp = t / OUTF, o = t % OUTF;
        float acc = dec_b[pp * OUTF + o];
        for (int h = 0; h < H; ++h) acc += s_g[h] * dec_w[(pp * H + h) * OUTF + o];
        s_lg[t] = acc;
    }
    __syncthreads();
    if (t < PP * OUTF) {
        const int pp = t / OUTF;
        float mx = -INFINITY;
        for (int o = 0; o < OUTF; ++o) mx = fmaxf(mx, s_lg[pp * OUTF + o]);
        float s = 0.0f;
        for (int o = 0; o < OUTF; ++o) s += expf(s_lg[pp * OUTF + o] - mx);
        out[t] = s_lg[t] - (mx + logf(s));
    }
}

extern "C" void kernel_launch(void* const* d_in, const int* in_sizes, int n_in,
                              void* d_out, int out_size, void* d_ws, size_t ws_size,
                              hipStream_t stream) {
    const float* xa        = (const float*)d_in[0];
    const float* fm        = (const float*)d_in[1];
    const int*   neighbors = (const int*)  d_in[2];
    const int*   nstart_p  = (const int*)  d_in[3];
    const float* enc_w     = (const float*)d_in[4];
    const float* enc_b     = (const float*)d_in[5];
    const float* ns_w      = (const float*)d_in[6];
    const float* ns_b      = (const float*)d_in[7];
    const float* nm_w      = (const float*)d_in[8];
    const float* nm_b      = (const float*)d_in[9];
    const float* act_w     = (const float*)d_in[10];
    const float* act_b     = (const float*)d_in[11];
    const float* dec_w     = (const float*)d_in[12];
    const float* dec_b     = (const float*)d_in[13];
    float* out = (float*)d_out;

    float* feats  = (float*)d_ws;                       // NN*H
    float* finalv = feats + NN * H;                     // NN*H
    float* qm     = finalv + NN * H;                    // QCAP*M
    float* nmbuf  = qm + (size_t)QCAP * M;              // PB*M
    _Float16* wnsB = (_Float16*)(nmbuf + PB * M);       // 128*WROW
    _Float16* wnmB = wnsB + 128 * WROW;
    unsigned short* qn = (unsigned short*)(wnmB + 128 * WROW);  // QCAP u16

    init_kernel<<<NN, 128, 0, stream>>>(xa, fm, enc_w, enc_b, nstart_p,
                                        feats, finalv, qm);
    pack_kernel<<<132, 256, 0, stream>>>(ns_w, nm_w, wnsB, wnmB);
    seq_kernel<<<1, NT, 0, stream>>>(neighbors, ns_b, nm_b,
                                     act_w, act_b, dec_w, dec_b, nstart_p,
                                     wnsB, wnmB,
                                     feats, finalv, qm, nmbuf, qn, out);
}

// Round 9
// 1190.701 us; speedup vs baseline: 5.3641x; 1.2065x over previous
//
#include <hip/hip_runtime.h>
#include <math.h>

#define NN 1000
#define INF_ 32
#define H 128
#define M 128
#define DEG 16
#define PP 2
#define OUTF 10
#define MAXM (10 * NN)        // scan length; head <= MAXM
#define QCAP (MAXM + DEG)     // only entries < MAXM are ever read
#define NT 512
#define PB 512                // max procs per window (= NT, no cut)
#define WROW 264              // padded halves per X/weight row (256+8)
#define NROW 136              // padded halves per NSh row (128+8)

typedef _Float16 half8 __attribute__((ext_vector_type(8)));
typedef float floatx4 __attribute__((ext_vector_type(4)));

// ws: feats_h[NN*H] f16 | finalv[NN*H] f32 | qm_h[QCAP*M] f16 | nmbuf_h[PB*M] f16
//     | wnsB[128*WROW] f16 | wnmB[128*WROW] f16 | qn[QCAP] u16

__global__ __launch_bounds__(128)
void init_kernel(const float* __restrict__ xa, const float* __restrict__ fm,
                 const float* __restrict__ enc_w, const float* __restrict__ enc_b,
                 const int* __restrict__ nstart_p,
                 _Float16* __restrict__ feats_h, float* __restrict__ finalv,
                 _Float16* __restrict__ qm_h) {
    int b = blockIdx.x, t = threadIdx.x;
    float acc = enc_b[t];
    const float* xr = xa + b * INF_;
#pragma unroll
    for (int k = 0; k < INF_; ++k) acc += xr[k] * enc_w[k * H + t];
    feats_h[b * H + t] = (_Float16)acc;     // same rounding point as R8 staging
    finalv[b * H + t] = 0.0f;
    if (b < nstart_p[0]) qm_h[(size_t)b * M + t] = (_Float16)fm[b * M + t];
}

// Pack weights fp16 transposed [n][k] with +8 pad: wB[n*WROW+k] = w[k][n].
__global__ __launch_bounds__(256)
void pack_kernel(const float* __restrict__ ns_w, const float* __restrict__ nm_w,
                 _Float16* __restrict__ wnsB, _Float16* __restrict__ wnmB) {
    const int idx = blockIdx.x * 256 + threadIdx.x;   // 128*WROW
    if (idx >= 128 * WROW) return;
    const int n = idx / WROW, k = idx % WROW;
    wnsB[idx] = (k < 256) ? (_Float16)ns_w[k * H + n] : (_Float16)0.0f;
    wnmB[idx] = (k < 256) ? (_Float16)nm_w[k * M + n] : (_Float16)0.0f;
}

// Rank-decomposed sequential ACT loop; batched matvec on the MFMA pipe.
// Full 512-entry windows (no candidate cap). fp16 state end-to-end
// (bit-identical to R8's staged-fp16 arithmetic).
__global__ __launch_bounds__(NT, 1)
void seq_kernel(const int* __restrict__ neighbors,
                const float* __restrict__ ns_b, const float* __restrict__ nm_b,
                const float* __restrict__ act_w, const float* __restrict__ act_b,
                const float* __restrict__ dec_w, const float* __restrict__ dec_b,
                const int* __restrict__ nstart_p,
                const _Float16* __restrict__ wnsB, const _Float16* __restrict__ wnmB,
                _Float16* __restrict__ feats_h, float* __restrict__ finalv,
                _Float16* __restrict__ qm_h, _Float16* __restrict__ nmbuf_h,
                unsigned short* __restrict__ qn, float* __restrict__ out) {
    __shared__ __align__(16) _Float16 s_wn[128 * WROW];  // 67584 B
    __shared__ __align__(16) _Float16 s_wm[128 * WROW];  // 67584 B
    __shared__ __align__(16) _Float16 s_Xh[16 * WROW];   // 8448 B
    __shared__ __align__(16) _Float16 s_NSh[16 * NROW];  // 4352 B
    __shared__ float s_tact[NN];                         // 4000 B
    __shared__ int   s_mark[NN];                         // 4000 B (order/readout overlaid)
    __shared__ float s_actw[H + M];
    __shared__ float s_nsb[H];
    __shared__ float s_nmb[M];
    __shared__ float s_rz[16];
    __shared__ float s_rna[16];
    __shared__ unsigned short s_rnode[PB];               // 1024 B
    __shared__ unsigned short s_rentry[PB];              // 1024 B
    __shared__ short s_eslot[NT];                        // 1024 B
    __shared__ unsigned char s_flag[NT];                 // 512 B
    __shared__ int   s_wb[8], s_wc[8];

    short* s_order = (short*)s_mark;                     // overlay: mark[0..255]
    float* s_g  = (float*)(s_mark + 256);                // overlay: readout only
    float* s_lg = (float*)(s_mark + 256 + 128);

    const int t = threadIdx.x;
    const int lane = t & 63, wid = t >> 6;
    const int quad = lane >> 4, lm = lane & 15;
    const int colw = (wid << 4) + lm;                    // this thread's output col
    const int sg = t & 31;                               // gate sub-lane
    const int nstart = nstart_p[0];

    {   // one-time: weights into LDS (uint4 copies)
        const uint4* s0 = (const uint4*)wnsB; uint4* d0 = (uint4*)s_wn;
        const uint4* s1 = (const uint4*)wnmB; uint4* d1 = (uint4*)s_wm;
        for (int i = t; i < 128 * WROW / 8; i += NT) { d0[i] = s0[i]; d1[i] = s1[i]; }
    }
    for (int i = t; i < NN; i += NT) { s_tact[i] = 0.0f; s_mark[i] = 0x7fffffff; }
    for (int i = t; i < nstart; i += NT) qn[i] = (unsigned short)i;
    if (t < H + M) s_actw[t] = act_w[t];
    if (t < H) { s_nsb[t] = ns_b[t]; s_nmb[t] = nm_b[t]; }
    const float actb = act_b[0];
    __syncthreads();
    const float nsb_c = s_nsb[colw];
    const float nmb_c = s_nmb[colw];
    float aw[8];                                         // gate coeffs in regs
#pragma unroll
    for (int j = 0; j < 8; ++j) aw[j] = s_actw[sg * 8 + j];

    int head = 0, tail = nstart;
    for (;;) {
        const int lim = min(tail, MAXM);
        if (head >= lim) break;
        const int W = min(NT, lim - head);

        // ---- classify candidates; clear flags; repair order-overlaid mark ----
        int node = 0; bool cand0 = false;
        if (t < W) {
            node = (int)qn[head + t];
            cand0 = (s_tact[node] <= 1.0f - 1e-7f);
        }
        s_flag[t] = 0;
        if (t < 256) s_mark[t] = 0x7fffffff;             // order overlay repair
        __syncthreads();                                 // B1
        bool remaining = cand0;

        // ---------------- rank rounds ----------------
        int base = 0;
        for (;;) {
            const bool rem2 = remaining && (s_tact[node] <= 1.0f - 1e-7f);
            if (rem2) atomicMin(&s_mark[node], t);
            __syncthreads();                             // R1
            const bool win = rem2 && (s_mark[node] == t);
            const unsigned long long mw = __ballot(win);
            if (lane == 0) s_wb[wid] = __popcll(mw);
            __syncthreads();                             // R2
            int Pr = 0, preb = 0;
#pragma unroll
            for (int w = 0; w < 8; ++w) { Pr += s_wb[w]; preb += (w < wid) ? s_wb[w] : 0; }
            if (Pr == 0) break;
            const int wrank = preb + __popcll(mw & ((1ull << lane) - 1ull));
            if (win) {
                s_rnode[wrank] = (unsigned short)node;
                s_rentry[wrank] = (unsigned short)t;
                s_eslot[t] = (short)(base + wrank);
                s_flag[t] = 1;
            }
            if (rem2) s_mark[node] = 0x7fffffff;         // reset touched entries
            remaining = rem2 && !win;
            __syncthreads();                             // R3

            // ---- chunks of 16 rows ----
            for (int c0 = 0; c0 < Pr; c0 += 16) {
                const int Pc = min(16, Pr - c0);
                // stage Xh rows — pure fp16 uint4 copies
                for (int idx = t; idx < Pc * 32; idx += NT) {
                    const int r = idx >> 5, c8 = idx & 31;
                    const int nr = (int)s_rnode[c0 + r];
                    const int hp = head + (int)s_rentry[c0 + r];
                    const uint4 v = (c8 < 16)
                        ? ((const uint4*)(feats_h + (size_t)nr * H))[c8]
                        : ((const uint4*)(qm_h + (size_t)hp * M))[c8 - 16];
                    *(uint4*)(s_Xh + r * WROW + (c8 << 3)) = v;
                }
                __syncthreads();                         // A: Xh ready

                // gate partials (f32 math on fp16 x; coeffs in regs)
                {
                    const int r = t >> 5;
                    if (r < Pc) {
                        const half8 hv = *(const half8*)(s_Xh + r * WROW + (sg << 3));
                        float p = 0.0f;
#pragma unroll
                        for (int j = 0; j < 8; ++j) p += (float)hv[j] * aw[j];
#pragma unroll
                        for (int off = 16; off > 0; off >>= 1) p += __shfl_down(p, off, 32);
                        if (sg == 0) s_rz[r] = p;
                    }
                }
                // phase 1 MFMA: ns (K=256) + nm msg-half (K=128..256)
                floatx4 accn = {0.0f, 0.0f, 0.0f, 0.0f};
                floatx4 accm = {0.0f, 0.0f, 0.0f, 0.0f};
                {
                    const _Float16* xrow = s_Xh + lm * WROW + (quad << 3);
                    const _Float16* bn = s_wn + colw * WROW + (quad << 3);
                    const _Float16* bm = s_wm + colw * WROW + (quad << 3);
                    half8 a[8];
#pragma unroll
                    for (int c = 0; c < 8; ++c) a[c] = *(const half8*)(xrow + (c << 5));
#pragma unroll
                    for (int c = 0; c < 8; ++c)
                        accn = __builtin_amdgcn_mfma_f32_16x16x32_f16(
                            a[c], *(const half8*)(bn + (c << 5)), accn, 0, 0, 0);
#pragma unroll
                    for (int c = 4; c < 8; ++c)
                        accm = __builtin_amdgcn_mfma_f32_16x16x32_f16(
                            a[c], *(const half8*)(bm + (c << 5)), accm, 0, 0, 0);
                }
                float nsv[4];
#pragma unroll
                for (int i = 0; i < 4; ++i) {
                    const int r = (quad << 2) + i;
                    nsv[i] = fmaxf(accn[i] + nsb_c, 0.0f);
                    if (r < Pc) {
                        s_NSh[r * NROW + colw] = (_Float16)nsv[i];
                        feats_h[(size_t)s_rnode[c0 + r] * H + colw] = (_Float16)nsv[i];
                    }
                }
                __syncthreads();                         // B: NSh + rz ready

                // gate finalize + tact (distinct nodes per round)
                if (t < Pc) {
                    const float z = s_rz[t] + actb;
                    const float cnd = 1.0f / (1.0f + expf(-z));
                    const int nr = (int)s_rnode[c0 + t];
                    const float ta = s_tact[nr];
                    const float na = (ta + cnd > 1.0f) ? (1.0f - ta) : cnd;
                    s_rna[t] = na;
                    s_tact[nr] = ta + na;
                }
                // phase 2 MFMA: nm ns-half (K=0..128)
                {
                    const _Float16* nrow = s_NSh + lm * NROW + (quad << 3);
                    const _Float16* bm = s_wm + colw * WROW + (quad << 3);
#pragma unroll
                    for (int c = 0; c < 4; ++c)
                        accm = __builtin_amdgcn_mfma_f32_16x16x32_f16(
                            *(const half8*)(nrow + (c << 5)),
                            *(const half8*)(bm + (c << 5)), accm, 0, 0, 0);
                }
                // nmbuf write needs only accm (no barrier)
#pragma unroll
                for (int i = 0; i < 4; ++i) {
                    const int r = (quad << 2) + i;
                    if (r < Pc)
                        nmbuf_h[(size_t)(base + c0 + r) * M + colw] =
                            (_Float16)(accm[i] + nmb_c);
                }
                __syncthreads();                         // C: rna ready

                // epilogue: finalv (f32 accum)
#pragma unroll
                for (int i = 0; i < 4; ++i) {
                    const int r = (quad << 2) + i;
                    if (r < Pc)
                        finalv[(size_t)s_rnode[c0 + r] * H + colw] += nsv[i] * s_rna[r];
                }
            }
            base += Pr;
            __syncthreads();                             // R7: epilogue done before next round
        }

        // ---------------- enqueue (queue order via prefix over flags) ----------------
        const bool pf = (s_flag[t] != 0);
        const unsigned long long mf = __ballot(pf);
        if (lane == 0) s_wc[wid] = __popcll(mf);
        __syncthreads();                                 // B3
        int T = 0, prec = 0;
#pragma unroll
        for (int w = 0; w < 8; ++w) { T += s_wc[w]; prec += (w < wid) ? s_wc[w] : 0; }
        if (pf) s_order[prec + __popcll(mf & ((1ull << lane) - 1ull))] = (short)t;
        __syncthreads();                                 // B4
        for (int idx = t; idx < T * DEG; idx += NT) {
            const int j = idx >> 4;
            const int nd = (int)qn[head + (int)s_order[j]];
            const int q = tail + idx;
            if (q < QCAP)
                qn[q] = (unsigned short)neighbors[nd * DEG + (idx & 15)];
        }
        {   // qm copy: fp16, 16 uint4 per queue row
            uint4* qm4 = (uint4*)qm_h;
            const uint4* nb4 = (const uint4*)nmbuf_h;
            const int total = T * DEG * 16;
            for (int idx = t; idx < total; idx += NT) {
                const int c = idx & 15;
                const int row = idx >> 4;                // 0 .. T*16-1
                const int slot = (int)s_eslot[(int)s_order[row >> 4]];
                const int q = tail + row;
                if (q < QCAP)
                    qm4[(size_t)q * 16 + c] = nb4[(size_t)slot * 16 + c];
            }
        }
        tail += DEG * T;
        head += W;
        __syncthreads();                                 // B5
    }

    // ---- readout (g/lg overlaid on dead mark region) ----
    if (t < H) {
        float g0 = 0, g1 = 0, g2 = 0, g3 = 0;
        for (int n = 0; n < NN; n += 4) {
            g0 += finalv[(n + 0) * H + t];
            g1 += finalv[(n + 1) * H + t];
            g2 += finalv[(n + 2) * H + t];
            g3 += finalv[(n + 3) * H + t];
        }
        s_g[t] = (g0 + g1) + (g2 + g3);
    }
    __syncthreads();
    if (t < PP * OUTF) {
        const int pp = t / OUTF, o = t % OUTF;
        float acc = dec_b[pp * OUTF + o];
        for (int h = 0; h < H; ++h) acc += s_g[h] * dec_w[(pp * H + h) * OUTF + o];
        s_lg[t] = acc;
    }
    __syncthreads();
    if (t < PP * OUTF) {
        const int pp = t / OUTF;
        float mx = -INFINITY;
        for (int o = 0; o < OUTF; ++o) mx = fmaxf(mx, s_lg[pp * OUTF + o]);
        float s = 0.0f;
        for (int o = 0; o < OUTF; ++o) s += expf(s_lg[pp * OUTF + o] - mx);
        out[t] = s_lg[t] - (mx + logf(s));
    }
}

extern "C" void kernel_launch(void* const* d_in, const int* in_sizes, int n_in,
                              void* d_out, int out_size, void* d_ws, size_t ws_size,
                              hipStream_t stream) {
    const float* xa        = (const float*)d_in[0];
    const float* fm        = (const float*)d_in[1];
    const int*   neighbors = (const int*)  d_in[2];
    const int*   nstart_p  = (const int*)  d_in[3];
    const float* enc_w     = (const float*)d_in[4];
    const float* enc_b     = (const float*)d_in[5];
    const float* ns_w      = (const float*)d_in[6];
    const float* ns_b      = (const float*)d_in[7];
    const float* nm_w      = (const float*)d_in[8];
    const float* nm_b      = (const float*)d_in[9];
    const float* act_w     = (const float*)d_in[10];
    const float* act_b     = (const float*)d_in[11];
    const float* dec_w     = (const float*)d_in[12];
    const float* dec_b     = (const float*)d_in[13];
    float* out = (float*)d_out;

    char* w = (char*)d_ws;
    _Float16* feats_h = (_Float16*)w;                 w += (size_t)NN * H * 2;
    float*    finalv  = (float*)w;                    w += (size_t)NN * H * 4;
    _Float16* qm_h    = (_Float16*)w;                 w += (size_t)QCAP * M * 2;
    _Float16* nmbuf_h = (_Float16*)w;                 w += (size_t)PB * M * 2;
    _Float16* wnsB    = (_Float16*)w;                 w += (size_t)128 * WROW * 2;
    _Float16* wnmB    = (_Float16*)w;                 w += (size_t)128 * WROW * 2;
    unsigned short* qn = (unsigned short*)w;

    init_kernel<<<NN, 128, 0, stream>>>(xa, fm, enc_w, enc_b, nstart_p,
                                        feats_h, finalv, qm_h);
    pack_kernel<<<132, 256, 0, stream>>>(ns_w, nm_w, wnsB, wnmB);
    seq_kernel<<<1, NT, 0, stream>>>(neighbors, ns_b, nm_b,
                                     act_w, act_b, dec_w, dec_b, nstart_p,
                                     wnsB, wnmB,
                                     feats_h, finalv, qm_h, nmbuf_h, qn, out);
}

// Round 10
// 794.117 us; speedup vs baseline: 8.0429x; 1.4994x over previous
//
#include <hip/hip_runtime.h>
#include <math.h>

#define NN 1000
#define INF_ 32
#define H 128
#define M 128
#define DEG 16
#define PP 2
#define OUTF 10
#define MAXM (10 * NN)        // scan length; head <= MAXM
#define QCAP (MAXM + DEG)     // only entries < MAXM are ever read
#define NSLOT (MAXM + 128)    // nmbuf rows: nstart + total procs <= 64+10000
#define NT 512
#define WROW 264              // padded halves per X/weight row (256+8)
#define NROW 136              // padded halves per NSh row (128+8)

typedef _Float16 half8 __attribute__((ext_vector_type(8)));
typedef float floatx4 __attribute__((ext_vector_type(4)));

// LDS-only barrier: publishes LDS writes without draining global (vmcnt) queue.
__device__ __forceinline__ void bar_lds() {
    asm volatile("s_waitcnt lgkmcnt(0)\n\ts_barrier" ::: "memory");
}

// ws: feats_h[NN*H] f16 | finalv[NN*H] f32 | nmbuf_h[NSLOT*M] f16
//     | wnsB f16 | wnmB f16 | qpack[QCAP] u32 (node | slot<<16)

__global__ __launch_bounds__(128)
void init_kernel(const float* __restrict__ xa, const float* __restrict__ fm,
                 const float* __restrict__ enc_w, const float* __restrict__ enc_b,
                 const int* __restrict__ nstart_p,
                 _Float16* __restrict__ feats_h, float* __restrict__ finalv,
                 _Float16* __restrict__ nmbuf_h) {
    int b = blockIdx.x, t = threadIdx.x;
    float acc = enc_b[t];
    const float* xr = xa + b * INF_;
#pragma unroll
    for (int k = 0; k < INF_; ++k) acc += xr[k] * enc_w[k * H + t];
    feats_h[b * H + t] = (_Float16)acc;     // same rounding point as R8/R9
    finalv[b * H + t] = 0.0f;
    if (b < nstart_p[0]) nmbuf_h[(size_t)b * M + t] = (_Float16)fm[b * M + t];
}

// Pack weights fp16 transposed [n][k] with +8 pad: wB[n*WROW+k] = w[k][n].
__global__ __launch_bounds__(256)
void pack_kernel(const float* __restrict__ ns_w, const float* __restrict__ nm_w,
                 _Float16* __restrict__ wnsB, _Float16* __restrict__ wnmB) {
    const int idx = blockIdx.x * 256 + threadIdx.x;   // 128*WROW
    if (idx >= 128 * WROW) return;
    const int n = idx / WROW, k = idx % WROW;
    wnsB[idx] = (k < 256) ? (_Float16)ns_w[k * H + n] : (_Float16)0.0f;
    wnmB[idx] = (k < 256) ? (_Float16)nm_w[k * M + n] : (_Float16)0.0f;
}

// Rank-decomposed sequential ACT loop; MFMA matvecs; LDS-only fine barriers;
// messages stored once in nmbuf with queue slot-indirection.
__global__ __launch_bounds__(NT, 1)
void seq_kernel(const int* __restrict__ neighbors,
                const float* __restrict__ ns_b, const float* __restrict__ nm_b,
                const float* __restrict__ act_w, const float* __restrict__ act_b,
                const float* __restrict__ dec_w, const float* __restrict__ dec_b,
                const int* __restrict__ nstart_p,
                const _Float16* __restrict__ wnsB, const _Float16* __restrict__ wnmB,
                _Float16* __restrict__ feats_h, float* __restrict__ finalv,
                _Float16* __restrict__ nmbuf_h, unsigned int* __restrict__ qpack,
                float* __restrict__ out) {
    __shared__ __align__(16) _Float16 s_wn[128 * WROW];  // 67584 B
    __shared__ __align__(16) _Float16 s_wm[128 * WROW];  // 67584 B
    __shared__ __align__(16) _Float16 s_Xh[16 * WROW];   // 8448 B
    __shared__ __align__(16) _Float16 s_NSh[16 * NROW];  // 4352 B
    __shared__ float s_tact[NN];                         // 4000 B
    __shared__ int   s_mark[NN];                         // 4000 B (order/readout overlay)
    __shared__ float s_actw[H + M];
    __shared__ float s_nsb[H];
    __shared__ float s_nmb[M];
    __shared__ float s_rz[16];
    __shared__ float s_rna[16];
    __shared__ unsigned short s_rnode[NT];               // 1024 B (rows, rank order)
    __shared__ unsigned short s_rslot[NT];               // 1024 B (msg slot per row)
    __shared__ unsigned int  s_enq[NT];                  // 2048 B node|newslot<<16 per entry
    __shared__ unsigned char s_flag[NT];                 // 512 B
    __shared__ int s_wb[8], s_wc[8];

    short* s_order = (short*)s_mark;                     // overlay: mark[0..255]
    float* s_g  = (float*)(s_mark + 256);                // overlay: readout only
    float* s_lg = (float*)(s_mark + 256 + 128);

    const int t = threadIdx.x;
    const int lane = t & 63, wid = t >> 6;
    const int quad = lane >> 4, lm = lane & 15;
    const int colw = (wid << 4) + lm;                    // this thread's output col
    const int sg = t & 31;                               // gate sub-lane
    const int r16 = t >> 5, c8 = t & 31;                 // staging coords (16x32)
    const int nstart = nstart_p[0];

    {   // one-time: weights into LDS
        const uint4* s0 = (const uint4*)wnsB; uint4* d0 = (uint4*)s_wn;
        const uint4* s1 = (const uint4*)wnmB; uint4* d1 = (uint4*)s_wm;
        for (int i = t; i < 128 * WROW / 8; i += NT) { d0[i] = s0[i]; d1[i] = s1[i]; }
    }
    for (int i = t; i < NN; i += NT) { s_tact[i] = 0.0f; s_mark[i] = 0x7fffffff; }
    for (int i = t; i < nstart; i += NT) qpack[i] = (unsigned)i | ((unsigned)i << 16);
    if (t < H + M) s_actw[t] = act_w[t];
    if (t < H) { s_nsb[t] = ns_b[t]; s_nmb[t] = nm_b[t]; }
    const float actb = act_b[0];
    __syncthreads();
    const float nsb_c = s_nsb[colw];
    const float nmb_c = s_nmb[colw];
    float aw[8];
#pragma unroll
    for (int j = 0; j < 8; ++j) aw[j] = s_actw[sg * 8 + j];

    int head = 0, tail = nstart, gbase = nstart;
    for (;;) {
        const int lim = min(tail, MAXM);
        if (head >= lim) break;
        const int W = min(NT, lim - head);

        // ---- classify; clear flags; repair order-overlaid mark ----
        int node = 0, slotv = 0; bool cand0 = false;
        if (t < W) {
            const unsigned v = qpack[head + t];
            node = (int)(v & 0xffffu);
            slotv = (int)(v >> 16);
            cand0 = (s_tact[node] <= 1.0f - 1e-7f);
        }
        s_flag[t] = 0;
        if (t < 256) s_mark[t] = 0x7fffffff;
        bar_lds();                                       // B1
        bool remaining = cand0;

        // ---------------- rank rounds ----------------
        int base = 0;
        for (;;) {
            const bool rem2 = remaining && (s_tact[node] <= 1.0f - 1e-7f);
            if (rem2) atomicMin(&s_mark[node], t);
            bar_lds();                                   // R1
            const bool win = rem2 && (s_mark[node] == t);
            const unsigned long long mw = __ballot(win);
            if (lane == 0) s_wb[wid] = __popcll(mw);
            bar_lds();                                   // R2
            int Pr = 0, preb = 0;
#pragma unroll
            for (int w = 0; w < 8; ++w) { Pr += s_wb[w]; preb += (w < wid) ? s_wb[w] : 0; }
            if (Pr == 0) break;
            const int wrank = preb + __popcll(mw & ((1ull << lane) - 1ull));
            if (win) {
                s_rnode[wrank] = (unsigned short)node;
                s_rslot[wrank] = (unsigned short)slotv;
                s_enq[t] = (unsigned)node | ((unsigned)(gbase + base + wrank) << 16);
                s_flag[t] = 1;
            }
            if (rem2) s_mark[node] = 0x7fffffff;         // reset touched entries
            remaining = rem2 && !win;
            bar_lds();                                   // R3: rnode/rslot ready

            // ---- prefetch chunk 0 (X row uint4 + finalv vals) ----
            uint4 px; float fv[4];
            {
                const int rr = min(r16, Pr - 1);
                const int nr = (int)s_rnode[rr];
                const int sl = (int)s_rslot[rr];
                px = (c8 < 16)
                    ? ((const uint4*)(feats_h + (size_t)nr * H))[c8]
                    : ((const uint4*)(nmbuf_h + (size_t)sl * M))[c8 - 16];
#pragma unroll
                for (int i = 0; i < 4; ++i) {
                    const int rr2 = min((quad << 2) + i, Pr - 1);
                    fv[i] = finalv[(size_t)s_rnode[rr2] * H + colw];
                }
            }
            // ---- chunks of 16 rows, software-pipelined staging ----
            for (int c0 = 0; c0 < Pr; c0 += 16) {
                const int Pc = min(16, Pr - c0);
                *(uint4*)(s_Xh + r16 * WROW + (c8 << 3)) = px;
                bar_lds();                               // A: Xh(c) ready
                const bool hasnext = (c0 + 16) < Pr;
                uint4 pxn; float fvn[4];
                if (hasnext) {                           // issue next-chunk loads
                    const int rr = min(c0 + 16 + r16, Pr - 1);
                    const int nr = (int)s_rnode[rr];
                    const int sl = (int)s_rslot[rr];
                    pxn = (c8 < 16)
                        ? ((const uint4*)(feats_h + (size_t)nr * H))[c8]
                        : ((const uint4*)(nmbuf_h + (size_t)sl * M))[c8 - 16];
#pragma unroll
                    for (int i = 0; i < 4; ++i) {
                        const int rr2 = min(c0 + 16 + (quad << 2) + i, Pr - 1);
                        fvn[i] = finalv[(size_t)s_rnode[rr2] * H + colw];
                    }
                }
                // gate partials (f32 math on fp16 x; coeffs in regs)
                {
                    const int r = t >> 5;
                    if (r < Pc) {
                        const half8 hv = *(const half8*)(s_Xh + r * WROW + (sg << 3));
                        float p = 0.0f;
#pragma unroll
                        for (int j = 0; j < 8; ++j) p += (float)hv[j] * aw[j];
#pragma unroll
                        for (int off = 16; off > 0; off >>= 1) p += __shfl_down(p, off, 32);
                        if (sg == 0) s_rz[r] = p;
                    }
                }
                // phase 1 MFMA: ns (K=256) + nm msg-half (K=128..256)
                floatx4 accn = {0.0f, 0.0f, 0.0f, 0.0f};
                floatx4 accm = {0.0f, 0.0f, 0.0f, 0.0f};
                {
                    const _Float16* xrow = s_Xh + lm * WROW + (quad << 3);
                    const _Float16* bn = s_wn + colw * WROW + (quad << 3);
                    const _Float16* bm = s_wm + colw * WROW + (quad << 3);
                    half8 a[8];
#pragma unroll
                    for (int c = 0; c < 8; ++c) a[c] = *(const half8*)(xrow + (c << 5));
#pragma unroll
                    for (int c = 0; c < 8; ++c)
                        accn = __builtin_amdgcn_mfma_f32_16x16x32_f16(
                            a[c], *(const half8*)(bn + (c << 5)), accn, 0, 0, 0);
#pragma unroll
                    for (int c = 4; c < 8; ++c)
                        accm = __builtin_amdgcn_mfma_f32_16x16x32_f16(
                            a[c], *(const half8*)(bm + (c << 5)), accm, 0, 0, 0);
                }
                float nsv[4];
#pragma unroll
                for (int i = 0; i < 4; ++i) {
                    const int r = (quad << 2) + i;
                    nsv[i] = fmaxf(accn[i] + nsb_c, 0.0f);
                    if (r < Pc) {
                        s_NSh[r * NROW + colw] = (_Float16)nsv[i];
                        feats_h[(size_t)s_rnode[c0 + r] * H + colw] = (_Float16)nsv[i];
                    }
                }
                bar_lds();                               // B: Xh reads done; NSh+rz ready
                // gate finalize + tact (distinct nodes per round)
                if (t < Pc) {
                    const float z = s_rz[t] + actb;
                    const float cnd = 1.0f / (1.0f + expf(-z));
                    const int nr = (int)s_rnode[c0 + t];
                    const float ta = s_tact[nr];
                    const float na = (ta + cnd > 1.0f) ? (1.0f - ta) : cnd;
                    s_rna[t] = na;
                    s_tact[nr] = ta + na;
                }
                // phase 2 MFMA: nm ns-half (K=0..128); nmbuf store
                {
                    const _Float16* nrow = s_NSh + lm * NROW + (quad << 3);
                    const _Float16* bm = s_wm + colw * WROW + (quad << 3);
#pragma unroll
                    for (int c = 0; c < 4; ++c)
                        accm = __builtin_amdgcn_mfma_f32_16x16x32_f16(
                            *(const half8*)(nrow + (c << 5)),
                            *(const half8*)(bm + (c << 5)), accm, 0, 0, 0);
                }
#pragma unroll
                for (int i = 0; i < 4; ++i) {
                    const int r = (quad << 2) + i;
                    if (r < Pc)
                        nmbuf_h[(size_t)(gbase + base + c0 + r) * M + colw] =
                            (_Float16)(accm[i] + nmb_c);
                }
                bar_lds();                               // C: rna ready
                // epilogue: finalv via prefetched values (exact += semantics)
#pragma unroll
                for (int i = 0; i < 4; ++i) {
                    const int r = (quad << 2) + i;
                    if (r < Pc)
                        finalv[(size_t)s_rnode[c0 + r] * H + colw] =
                            fv[i] + nsv[i] * s_rna[r];
                }
                if (hasnext) {
                    px = pxn;
#pragma unroll
                    for (int i = 0; i < 4; ++i) fv[i] = fvn[i];
                }
            }
            base += Pr;
            __syncthreads();       // R7 (full): drain feats/nmbuf/finalv stores
        }

        // ---------------- enqueue (queue order via prefix over flags) ----------------
        const bool pf = (s_flag[t] != 0);
        const unsigned long long mf = __ballot(pf);
        if (lane == 0) s_wc[wid] = __popcll(mf);
        bar_lds();                                       // B3
        int T = 0, prec = 0;
#pragma unroll
        for (int w = 0; w < 8; ++w) { T += s_wc[w]; prec += (w < wid) ? s_wc[w] : 0; }
        if (pf) s_order[prec + __popcll(mf & ((1ull << lane) - 1ull))] = (short)t;
        bar_lds();                                       // B4
        for (int idx = t; idx < T * DEG; idx += NT) {
            const int e = (int)s_order[idx >> 4];
            const unsigned v = s_enq[e];
            const int nd = (int)(v & 0xffffu);
            const unsigned slot = v >> 16;
            const int q = tail + idx;
            if (q < QCAP)
                qpack[q] = (unsigned)neighbors[nd * DEG + (idx & 15)] | (slot << 16);
        }
        tail += DEG * T;
        gbase += T;
        head += W;
        __syncthreads();                                 // B5 (full): qpack visible
    }

    // ---- readout (g/lg overlaid on dead mark region) ----
    if (t < H) {
        float g0 = 0, g1 = 0, g2 = 0, g3 = 0;
        for (int n = 0; n < NN; n += 4) {
            g0 += finalv[(n + 0) * H + t];
            g1 += finalv[(n + 1) * H + t];
            g2 += finalv[(n + 2) * H + t];
            g3 += finalv[(n + 3) * H + t];
        }
        s_g[t] = (g0 + g1) + (g2 + g3);
    }
    __syncthreads();
    if (t < PP * OUTF) {
        const int pp = t / OUTF, o = t % OUTF;
        float acc = dec_b[pp * OUTF + o];
        for (int h = 0; h < H; ++h) acc += s_g[h] * dec_w[(pp * H + h) * OUTF + o];
        s_lg[t] = acc;
    }
    __syncthreads();
    if (t < PP * OUTF) {
        const int pp = t / OUTF;
        float mx = -INFINITY;
        for (int o = 0; o < OUTF; ++o) mx = fmaxf(mx, s_lg[pp * OUTF + o]);
        float s = 0.0f;
        for (int o = 0; o < OUTF; ++o) s += expf(s_lg[pp * OUTF + o] - mx);
        out[t] = s_lg[t] - (mx + logf(s));
    }
}

extern "C" void kernel_launch(void* const* d_in, const int* in_sizes, int n_in,
                              void* d_out, int out_size, void* d_ws, size_t ws_size,
                              hipStream_t stream) {
    const float* xa        = (const float*)d_in[0];
    const float* fm        = (const float*)d_in[1];
    const int*   neighbors = (const int*)  d_in[2];
    const int*   nstart_p  = (const int*)  d_in[3];
    const float* enc_w     = (const float*)d_in[4];
    const float* enc_b     = (const float*)d_in[5];
    const float* ns_w      = (const float*)d_in[6];
    const float* ns_b      = (const float*)d_in[7];
    const float* nm_w      = (const float*)d_in[8];
    const float* nm_b      = (const float*)d_in[9];
    const float* act_w     = (const float*)d_in[10];
    const float* act_b     = (const float*)d_in[11];
    const float* dec_w     = (const float*)d_in[12];
    const float* dec_b     = (const float*)d_in[13];
    float* out = (float*)d_out;

    char* w = (char*)d_ws;
    _Float16* feats_h = (_Float16*)w;                 w += (size_t)NN * H * 2;
    float*    finalv  = (float*)w;                    w += (size_t)NN * H * 4;
    _Float16* nmbuf_h = (_Float16*)w;                 w += (size_t)NSLOT * M * 2;
    _Float16* wnsB    = (_Float16*)w;                 w += (size_t)128 * WROW * 2;
    _Float16* wnmB    = (_Float16*)w;                 w += (size_t)128 * WROW * 2;
    unsigned int* qpack = (unsigned int*)w;

    init_kernel<<<NN, 128, 0, stream>>>(xa, fm, enc_w, enc_b, nstart_p,
                                        feats_h, finalv, nmbuf_h);
    pack_kernel<<<132, 256, 0, stream>>>(ns_w, nm_w, wnsB, wnmB);
    seq_kernel<<<1, NT, 0, stream>>>(neighbors, ns_b, nm_b,
                                     act_w, act_b, dec_w, dec_b, nstart_p,
                                     wnsB, wnmB,
                                     feats_h, finalv, nmbuf_h, qpack, out);
}

// Round 11
// 673.714 us; speedup vs baseline: 9.4803x; 1.1787x over previous
//
#include <hip/hip_runtime.h>
#include <math.h>

#define NN 1000
#define INF_ 32
#define H 128
#define M 128
#define DEG 16
#define PP 2
#define OUTF 10
#define MAXM (10 * NN)        // scan length; head <= MAXM
#define QCAP (MAXM + DEG)     // only entries < MAXM are ever read
#define NSLOT (MAXM + 128)    // nmbuf rows: nstart + total procs
#define NT 512
#define WROW 264              // padded halves per X/weight row (256+8)
#define NROW 136              // padded halves per NSh row (128+8)

typedef _Float16 half8 __attribute__((ext_vector_type(8)));
typedef float floatx4 __attribute__((ext_vector_type(4)));

// LDS-only barrier: publishes LDS writes without draining global (vmcnt) queue.
__device__ __forceinline__ void bar_lds() {
    asm volatile("s_waitcnt lgkmcnt(0)\n\ts_barrier" ::: "memory");
}

// ws: feats_h[NN*H] f16 | finalv[NN*H] f32 | nmbuf_h[NSLOT*M] f16
//     | wnsB f16 | wnmB f16 | qpack[QCAP] u32 (node | slot<<16)

__global__ __launch_bounds__(128)
void init_kernel(const float* __restrict__ xa, const float* __restrict__ fm,
                 const float* __restrict__ enc_w, const float* __restrict__ enc_b,
                 const int* __restrict__ nstart_p,
                 _Float16* __restrict__ feats_h, float* __restrict__ finalv,
                 _Float16* __restrict__ nmbuf_h) {
    int b = blockIdx.x, t = threadIdx.x;
    float acc = enc_b[t];
    const float* xr = xa + b * INF_;
#pragma unroll
    for (int k = 0; k < INF_; ++k) acc += xr[k] * enc_w[k * H + t];
    feats_h[b * H + t] = (_Float16)acc;     // same rounding point as R8/R9/R10
    finalv[b * H + t] = 0.0f;
    if (b < nstart_p[0]) nmbuf_h[(size_t)b * M + t] = (_Float16)fm[b * M + t];
}

// Pack weights fp16 transposed [n][k] with +8 pad: wB[n*WROW+k] = w[k][n].
__global__ __launch_bounds__(256)
void pack_kernel(const float* __restrict__ ns_w, const float* __restrict__ nm_w,
                 _Float16* __restrict__ wnsB, _Float16* __restrict__ wnmB) {
    const int idx = blockIdx.x * 256 + threadIdx.x;   // 128*WROW
    if (idx >= 128 * WROW) return;
    const int n = idx / WROW, k = idx % WROW;
    wnsB[idx] = (k < 256) ? (_Float16)ns_w[k * H + n] : (_Float16)0.0f;
    wnmB[idx] = (k < 256) ? (_Float16)nm_w[k * M + n] : (_Float16)0.0f;
}

// Rank-decomposed sequential ACT loop; MFMA matvecs with REGISTER-RESIDENT
// weight B-fragments (loop-invariant: (colw,quad) fixed per thread);
// LDS-only fine barriers; slot-indirected message queue.
__global__ __launch_bounds__(NT, 1)
void seq_kernel(const int* __restrict__ neighbors,
                const float* __restrict__ ns_b, const float* __restrict__ nm_b,
                const float* __restrict__ act_w, const float* __restrict__ act_b,
                const float* __restrict__ dec_w, const float* __restrict__ dec_b,
                const int* __restrict__ nstart_p,
                const _Float16* __restrict__ wnsB, const _Float16* __restrict__ wnmB,
                _Float16* __restrict__ feats_h, float* __restrict__ finalv,
                _Float16* __restrict__ nmbuf_h, unsigned int* __restrict__ qpack,
                float* __restrict__ out) {
    __shared__ __align__(16) _Float16 s_Xh[16 * WROW];   // 8448 B
    __shared__ __align__(16) _Float16 s_NSh[16 * NROW];  // 4352 B
    __shared__ float s_tact[NN];                         // 4000 B
    __shared__ int   s_mark[NN];                         // 4000 B (order/readout overlay)
    __shared__ float s_actw[H + M];
    __shared__ float s_nsb[H];
    __shared__ float s_nmb[M];
    __shared__ float s_rz[16];
    __shared__ float s_rna[16];
    __shared__ unsigned short s_rnode[NT];               // rows, rank order
    __shared__ unsigned short s_rslot[NT];               // msg slot per row
    __shared__ unsigned int  s_enq[NT];                  // node|newslot<<16 per entry
    __shared__ unsigned char s_flag[NT];
    __shared__ int s_wb[8], s_wc[8];

    short* s_order = (short*)s_mark;                     // overlay: mark[0..255]
    float* s_g  = (float*)(s_mark + 256);                // overlay: readout only
    float* s_lg = (float*)(s_mark + 256 + 128);

    const int t = threadIdx.x;
    const int lane = t & 63, wid = t >> 6;
    const int quad = lane >> 4, lm = lane & 15;
    const int colw = (wid << 4) + lm;                    // this thread's output col
    const int sg = t & 31;                               // gate sub-lane
    const int r16 = t >> 5, c8 = t & 31;                 // staging coords (16x32)
    const int nstart = nstart_p[0];

    // ---- one-time: weight B-fragments into registers (loop-invariant) ----
    half8 wbn[8], wbm[8];
#pragma unroll
    for (int c = 0; c < 8; ++c) {
        wbn[c] = *(const half8*)(wnsB + (size_t)colw * WROW + (c << 5) + (quad << 3));
        wbm[c] = *(const half8*)(wnmB + (size_t)colw * WROW + (c << 5) + (quad << 3));
    }

    for (int i = t; i < NN; i += NT) { s_tact[i] = 0.0f; s_mark[i] = 0x7fffffff; }
    for (int i = t; i < nstart; i += NT) qpack[i] = (unsigned)i | ((unsigned)i << 16);
    if (t < H + M) s_actw[t] = act_w[t];
    if (t < H) { s_nsb[t] = ns_b[t]; s_nmb[t] = nm_b[t]; }
    const float actb = act_b[0];
    __syncthreads();
    const float nsb_c = s_nsb[colw];
    const float nmb_c = s_nmb[colw];
    float aw[8];
#pragma unroll
    for (int j = 0; j < 8; ++j) aw[j] = s_actw[sg * 8 + j];

    int head = 0, tail = nstart, gbase = nstart;
    for (;;) {
        const int lim = min(tail, MAXM);
        if (head >= lim) break;
        const int W = min(NT, lim - head);

        // ---- classify; clear flags; repair order-overlaid mark ----
        int node = 0, slotv = 0; bool cand0 = false;
        if (t < W) {
            const unsigned v = qpack[head + t];
            node = (int)(v & 0xffffu);
            slotv = (int)(v >> 16);
            cand0 = (s_tact[node] <= 1.0f - 1e-7f);
        }
        s_flag[t] = 0;
        if (t < 256) s_mark[t] = 0x7fffffff;
        bar_lds();                                       // B1
        bool remaining = cand0;

        // ---------------- rank rounds ----------------
        int base = 0;
        for (;;) {
            const bool rem2 = remaining && (s_tact[node] <= 1.0f - 1e-7f);
            if (rem2) atomicMin(&s_mark[node], t);
            bar_lds();                                   // R1
            const bool win = rem2 && (s_mark[node] == t);
            const unsigned long long mw = __ballot(win);
            if (lane == 0) s_wb[wid] = __popcll(mw);
            bar_lds();                                   // R2
            int Pr = 0, preb = 0;
#pragma unroll
            for (int w = 0; w < 8; ++w) { Pr += s_wb[w]; preb += (w < wid) ? s_wb[w] : 0; }
            if (Pr == 0) break;
            const int wrank = preb + __popcll(mw & ((1ull << lane) - 1ull));
            if (win) {
                s_rnode[wrank] = (unsigned short)node;
                s_rslot[wrank] = (unsigned short)slotv;
                s_enq[t] = (unsigned)node | ((unsigned)(gbase + base + wrank) << 16);
                s_flag[t] = 1;
            }
            if (rem2) s_mark[node] = 0x7fffffff;         // reset touched entries
            remaining = rem2 && !win;
            bar_lds();                                   // R3: rnode/rslot ready

            // ---- prefetch chunk 0 (X row uint4 + finalv vals) ----
            uint4 px; float fv[4];
            {
                const int rr = min(r16, Pr - 1);
                const int nr = (int)s_rnode[rr];
                const int sl = (int)s_rslot[rr];
                px = (c8 < 16)
                    ? ((const uint4*)(feats_h + (size_t)nr * H))[c8]
                    : ((const uint4*)(nmbuf_h + (size_t)sl * M))[c8 - 16];
#pragma unroll
                for (int i = 0; i < 4; ++i) {
                    const int rr2 = min((quad << 2) + i, Pr - 1);
                    fv[i] = finalv[(size_t)s_rnode[rr2] * H + colw];
                }
            }
            // ---- chunks of 16 rows, software-pipelined staging ----
            for (int c0 = 0; c0 < Pr; c0 += 16) {
                const int Pc = min(16, Pr - c0);
                *(uint4*)(s_Xh + r16 * WROW + (c8 << 3)) = px;
                bar_lds();                               // A: Xh(c) ready
                const bool hasnext = (c0 + 16) < Pr;
                uint4 pxn; float fvn[4];
                if (hasnext) {                           // issue next-chunk loads
                    const int rr = min(c0 + 16 + r16, Pr - 1);
                    const int nr = (int)s_rnode[rr];
                    const int sl = (int)s_rslot[rr];
                    pxn = (c8 < 16)
                        ? ((const uint4*)(feats_h + (size_t)nr * H))[c8]
                        : ((const uint4*)(nmbuf_h + (size_t)sl * M))[c8 - 16];
#pragma unroll
                    for (int i = 0; i < 4; ++i) {
                        const int rr2 = min(c0 + 16 + (quad << 2) + i, Pr - 1);
                        fvn[i] = finalv[(size_t)s_rnode[rr2] * H + colw];
                    }
                }
                // gate partials (f32 math on fp16 x; coeffs in regs)
                {
                    const int r = t >> 5;
                    if (r < Pc) {
                        const half8 hv = *(const half8*)(s_Xh + r * WROW + (sg << 3));
                        float p = 0.0f;
#pragma unroll
                        for (int j = 0; j < 8; ++j) p += (float)hv[j] * aw[j];
#pragma unroll
                        for (int off = 16; off > 0; off >>= 1) p += __shfl_down(p, off, 32);
                        if (sg == 0) s_rz[r] = p;
                    }
                }
                // phase 1 MFMA: ns (K=256) + nm msg-half (K=128..256); B from regs
                floatx4 accn = {0.0f, 0.0f, 0.0f, 0.0f};
                floatx4 accm = {0.0f, 0.0f, 0.0f, 0.0f};
                {
                    const _Float16* xrow = s_Xh + lm * WROW + (quad << 3);
                    half8 a[8];
#pragma unroll
                    for (int c = 0; c < 8; ++c) a[c] = *(const half8*)(xrow + (c << 5));
#pragma unroll
                    for (int c = 0; c < 8; ++c)
                        accn = __builtin_amdgcn_mfma_f32_16x16x32_f16(
                            a[c], wbn[c], accn, 0, 0, 0);
#pragma unroll
                    for (int c = 4; c < 8; ++c)
                        accm = __builtin_amdgcn_mfma_f32_16x16x32_f16(
                            a[c], wbm[c], accm, 0, 0, 0);
                }
                float nsv[4];
#pragma unroll
                for (int i = 0; i < 4; ++i) {
                    const int r = (quad << 2) + i;
                    nsv[i] = fmaxf(accn[i] + nsb_c, 0.0f);
                    if (r < Pc) {
                        s_NSh[r * NROW + colw] = (_Float16)nsv[i];
                        feats_h[(size_t)s_rnode[c0 + r] * H + colw] = (_Float16)nsv[i];
                    }
                }
                bar_lds();                               // B: Xh reads done; NSh+rz ready
                // gate finalize + tact (distinct nodes per round)
                if (t < Pc) {
                    const float z = s_rz[t] + actb;
                    const float cnd = 1.0f / (1.0f + expf(-z));
                    const int nr = (int)s_rnode[c0 + t];
                    const float ta = s_tact[nr];
                    const float na = (ta + cnd > 1.0f) ? (1.0f - ta) : cnd;
                    s_rna[t] = na;
                    s_tact[nr] = ta + na;
                }
                // phase 2 MFMA: nm ns-half (K=0..128); B from regs; nmbuf store
                {
                    const _Float16* nrow = s_NSh + lm * NROW + (quad << 3);
#pragma unroll
                    for (int c = 0; c < 4; ++c)
                        accm = __builtin_amdgcn_mfma_f32_16x16x32_f16(
                            *(const half8*)(nrow + (c << 5)), wbm[c], accm, 0, 0, 0);
                }
#pragma unroll
                for (int i = 0; i < 4; ++i) {
                    const int r = (quad << 2) + i;
                    if (r < Pc)
                        nmbuf_h[(size_t)(gbase + base + c0 + r) * M + colw] =
                            (_Float16)(accm[i] + nmb_c);
                }
                bar_lds();                               // C: rna ready
                // epilogue: finalv via prefetched values (exact += semantics)
#pragma unroll
                for (int i = 0; i < 4; ++i) {
                    const int r = (quad << 2) + i;
                    if (r < Pc)
                        finalv[(size_t)s_rnode[c0 + r] * H + colw] =
                            fv[i] + nsv[i] * s_rna[r];
                }
                if (hasnext) {
                    px = pxn;
#pragma unroll
                    for (int i = 0; i < 4; ++i) fv[i] = fvn[i];
                }
            }
            base += Pr;
            __syncthreads();       // R7 (full): drain feats/nmbuf/finalv stores
        }

        // ---------------- enqueue (queue order via prefix over flags) ----------------
        const bool pf = (s_flag[t] != 0);
        const unsigned long long mf = __ballot(pf);
        if (lane == 0) s_wc[wid] = __popcll(mf);
        bar_lds();                                       // B3
        int T = 0, prec = 0;
#pragma unroll
        for (int w = 0; w < 8; ++w) { T += s_wc[w]; prec += (w < wid) ? s_wc[w] : 0; }
        if (pf) s_order[prec + __popcll(mf & ((1ull << lane) - 1ull))] = (short)t;
        bar_lds();                                       // B4
        for (int idx = t; idx < T * DEG; idx += NT) {
            const int e = (int)s_order[idx >> 4];
            const unsigned v = s_enq[e];
            const int nd = (int)(v & 0xffffu);
            const unsigned slot = v >> 16;
            const int q = tail + idx;
            if (q < QCAP)
                qpack[q] = (unsigned)neighbors[nd * DEG + (idx & 15)] | (slot << 16);
        }
        tail += DEG * T;
        gbase += T;
        head += W;
        __syncthreads();                                 // B5 (full): qpack visible
    }

    // ---- readout (g/lg overlaid on dead mark region) ----
    if (t < H) {
        float g0 = 0, g1 = 0, g2 = 0, g3 = 0;
        for (int n = 0; n < NN; n += 4) {
            g0 += finalv[(n + 0) * H + t];
            g1 += finalv[(n + 1) * H + t];
            g2 += finalv[(n + 2) * H + t];
            g3 += finalv[(n + 3) * H + t];
        }
        s_g[t] = (g0 + g1) + (g2 + g3);
    }
    __syncthreads();
    if (t < PP * OUTF) {
        const int pp = t / OUTF, o = t % OUTF;
        float acc = dec_b[pp * OUTF + o];
        for (int h = 0; h < H; ++h) acc += s_g[h] * dec_w[(pp * H + h) * OUTF + o];
        s_lg[t] = acc;
    }
    __syncthreads();
    if (t < PP * OUTF) {
        const int pp = t / OUTF;
        float mx = -INFINITY;
        for (int o = 0; o < OUTF; ++o) mx = fmaxf(mx, s_lg[pp * OUTF + o]);
        float s = 0.0f;
        for (int o = 0; o < OUTF; ++o) s += expf(s_lg[pp * OUTF + o] - mx);
        out[t] = s_lg[t] - (mx + logf(s));
    }
}

extern "C" void kernel_launch(void* const* d_in, const int* in_sizes, int n_in,
                              void* d_out, int out_size, void* d_ws, size_t ws_size,
                              hipStream_t stream) {
    const float* xa        = (const float*)d_in[0];
    const float* fm        = (const float*)d_in[1];
    const int*   neighbors = (const int*)  d_in[2];
    const int*   nstart_p  = (const int*)  d_in[3];
    const float* enc_w     = (const float*)d_in[4];
    const float* enc_b     = (const float*)d_in[5];
    const float* ns_w      = (const float*)d_in[6];
    const float* ns_b      = (const float*)d_in[7];
    const float* nm_w      = (const float*)d_in[8];
    const float* nm_b      = (const float*)d_in[9];
    const float* act_w     = (const float*)d_in[10];
    const float* act_b     = (const float*)d_in[11];
    const float* dec_w     = (const float*)d_in[12];
    const float* dec_b     = (const float*)d_in[13];
    float* out = (float*)d_out;

    char* w = (char*)d_ws;
    _Float16* feats_h = (_Float16*)w;                 w += (size_t)NN * H * 2;
    float*    finalv  = (float*)w;                    w += (size_t)NN * H * 4;
    _Float16* nmbuf_h = (_Float16*)w;                 w += (size_t)NSLOT * M * 2;
    _Float16* wnsB    = (_Float16*)w;                 w += (size_t)128 * WROW * 2;
    _Float16* wnmB    = (_Float16*)w;                 w += (size_t)128 * WROW * 2;
    unsigned int* qpack = (unsigned int*)w;

    init_kernel<<<NN, 128, 0, stream>>>(xa, fm, enc_w, enc_b, nstart_p,
                                        feats_h, finalv, nmbuf_h);
    pack_kernel<<<132, 256, 0, stream>>>(ns_w, nm_w, wnsB, wnmB);
    seq_kernel<<<1, NT, 0, stream>>>(neighbors, ns_b, nm_b,
                                     act_w, act_b, dec_w, dec_b, nstart_p,
                                     wnsB, wnmB,
                                     feats_h, finalv, nmbuf_h, qpack, out);
}